// Round 3
// baseline (2104.598 us; speedup 1.0000x reference)
//
#include <hip/hip_runtime.h>

typedef short shortx8 __attribute__((ext_vector_type(8)));   // 8 bf16 (4 VGPRs)
typedef float floatx4 __attribute__((ext_vector_type(4)));
typedef float floatx16 __attribute__((ext_vector_type(16)));
typedef unsigned short u16;

#define GLB(x) ((const __attribute__((address_space(1))) void*)(x))
#define LDSC(x) ((__attribute__((address_space(3))) void*)(x))

__device__ __forceinline__ float bf2f(u16 u) {
  unsigned x = ((unsigned)u) << 16;
  float f;
  __builtin_memcpy(&f, &x, 4);
  return f;
}
__device__ __forceinline__ u16 f2bf(float f) {
  unsigned x;
  __builtin_memcpy(&x, &f, 4);
  x += 0x7fffu + ((x >> 16) & 1u);   // RNE
  return (u16)(x >> 16);
}

// ---------------------------------------------------------------------------
// fp32 -> bf16 flat cast (X)
__global__ __launch_bounds__(256) void cast_bf16(const float* __restrict__ src,
                                                 u16* __restrict__ dst) {
  const size_t i = ((size_t)blockIdx.x * 256 + threadIdx.x) << 3;
  floatx4 a = *(const floatx4*)(src + i);
  floatx4 b = *(const floatx4*)(src + i + 4);
  shortx8 o;
#pragma unroll
  for (int e = 0; e < 4; ++e) {
    o[e] = (short)f2bf(a[e]);
    o[e + 4] = (short)f2bf(b[e]);
  }
  *(shortx8*)(dst + i) = o;
}

// ---------------------------------------------------------------------------
// fp32 [R][C] -> bf16 [C][R] tile transpose+cast (64x64 tiles via LDS)
__global__ __launch_bounds__(256) void transpose_cast(const float* __restrict__ src,
                                                      u16* __restrict__ dst,
                                                      int R, int C) {
  __shared__ u16 T[64 * 72];
  const int tiles_c = C >> 6;
  const int r0 = (blockIdx.x / tiles_c) << 6;
  const int c0 = (blockIdx.x % tiles_c) << 6;
  const int tid = threadIdx.x;
  const int rl = tid >> 4;
  const int cb = (tid & 15) << 2;
#pragma unroll
  for (int rr = 0; rr < 4; ++rr) {
    const int row = rr * 16 + rl;
    floatx4 v = *(const floatx4*)(src + (size_t)(r0 + row) * C + c0 + cb);
#pragma unroll
    for (int i = 0; i < 4; ++i) T[(cb + i) * 72 + row] = f2bf(v[i]);
  }
  __syncthreads();
#pragma unroll
  for (int ii = 0; ii < 2; ++ii) {
    const int chunk = tid + (ii << 8);
    const int cr = chunk >> 3;
    const int r8 = (chunk & 7) << 3;
    shortx8 v = *(const shortx8*)(T + cr * 72 + r8);
    *(shortx8*)(dst + (size_t)(c0 + cr) * R + r0 + r8) = v;
  }
}

// ---------------------------------------------------------------------------
// 256x256 bf16 GEMM, B^T layout: C = A[M][K] * B^T([N][K]).
// 32x32x16 MFMA. LDS: 2 buf x {A,B} x {k-slice0,k-slice1} units of
// [256 rows][32 k] (16KB each). Read-side bank fix: 16B-block index XOR
// (row>>1)&3 via pre-swizzled global source + same XOR on ds_read.
// Schedule: 4 phases/K-tile (one k-step of 16 each), 1 stage-unit/phase
// issued 1.5 tiles ahead, vmcnt(8) twice per tile, raw s_barrier, setprio.
#define BAR() asm volatile("s_barrier" ::: "memory")
#define WAITV8() asm volatile("s_waitcnt vmcnt(8)" ::: "memory")

template <int OUT32>
__global__ __launch_bounds__(512, 2) void gemm8(const u16* __restrict__ A,
                                                const u16* __restrict__ B,
                                                void* __restrict__ Cout,
                                                const float* __restrict__ bias,
                                                int M, int N, int K) {
  __shared__ u16 lds[8 * 8192];  // [buf][mat][ks][256*32] = 128 KiB

  const int nbm = M >> 8;
  const int nwg = nbm * (N >> 8);
  const int cpx = nwg >> 3;  // nwg % 8 == 0 for all our shapes
  const int wg = ((int)blockIdx.x & 7) * cpx + ((int)blockIdx.x >> 3);
  const int bm = wg % nbm;
  const int bn = wg / nbm;

  const int tid = threadIdx.x;
  const int lane = tid & 63;
  const int w = tid >> 6;        // 0..7
  const int wm = w >> 2;         // 0..1
  const int wn = w & 3;          // 0..3
  const int l31 = lane & 31;
  const int kh = lane >> 5;      // 0..1
  const int NT = K >> 6;

  const int lrow = lane >> 2;    // staging: 0..15
  const int lblk = lane & 3;

#define UNIT(buf, mat, ks) (lds + (((buf) * 4 + (mat) * 2 + (ks)) << 13))

  const u16* Abase = A + (size_t)bm * 256 * K;
  const u16* Bbase = B + (size_t)bn * 256 * K;

  auto STAGE = [&](int mat, int ks, int buf, int t) {
    const u16* gb = mat ? Bbase : Abase;
#pragma unroll
    for (int j = 0; j < 2; ++j) {
      const int row = (w * 2 + j) * 16 + lrow;
      const int sblk = lblk ^ ((row >> 1) & 3);
      const u16* src = gb + (size_t)row * K + (t << 6) + (ks << 5) + (sblk << 3);
      __builtin_amdgcn_global_load_lds(GLB(src),
                                       LDSC(UNIT(buf, mat, ks) + ((w * 2 + j) << 9)),
                                       16, 0, 0);
    }
  };
  // A-frag (32x32x16): row = wm*128+mi*32+l31, k = kstep*16 + kh*8 + e
  auto LDA = [&](int mi, int kstep, int buf) -> shortx8 {
    const int row = wm * 128 + mi * 32 + l31;
    const int blk = (((kstep & 1) << 1) + kh) ^ ((row >> 1) & 3);
    return *(const shortx8*)(UNIT(buf, 0, kstep >> 1) + row * 32 + (blk << 3));
  };
  auto LDB = [&](int ni, int kstep, int buf) -> shortx8 {
    const int row = wn * 64 + ni * 32 + l31;
    const int blk = (((kstep & 1) << 1) + kh) ^ ((row >> 1) & 3);
    return *(const shortx8*)(UNIT(buf, 1, kstep >> 1) + row * 32 + (blk << 3));
  };

  floatx16 acc[4][2] = {};

  // Prologue: tile0 all 4 units, tile1 k0 units (oldest-first).
  STAGE(0, 0, 0, 0); STAGE(1, 0, 0, 0);
  STAGE(0, 1, 0, 0); STAGE(1, 1, 0, 0);
  STAGE(0, 0, 1, 1); STAGE(1, 0, 1, 1);
  WAITV8();
  BAR();

  for (int T = 0; T < NT; ++T) {
    const int cur = T & 1, nxt = cur ^ 1;
    const int t1 = (T + 1 < NT) ? T + 1 : NT - 1;
    const int t2 = (T + 2 < NT) ? T + 2 : NT - 1;
    shortx8 af[4], bf[2];

#pragma unroll
    for (int p = 0; p < 4; ++p) {
#pragma unroll
      for (int mi = 0; mi < 4; ++mi) af[mi] = LDA(mi, p, cur);
#pragma unroll
      for (int ni = 0; ni < 2; ++ni) bf[ni] = LDB(ni, p, cur);
      // stage plan: p0->A-k1(T+1,nxt), p1->B-k1(T+1,nxt),
      //             p2->A-k0(T+2,cur), p3->B-k0(T+2,cur)
      if (p == 0) STAGE(0, 1, nxt, t1);
      else if (p == 1) STAGE(1, 1, nxt, t1);
      else if (p == 2) STAGE(0, 0, cur, t2);
      else STAGE(1, 0, cur, t2);
      BAR();
      __builtin_amdgcn_s_setprio(1);
#pragma unroll
      for (int mi = 0; mi < 4; ++mi)
#pragma unroll
        for (int ni = 0; ni < 2; ++ni)
          acc[mi][ni] = __builtin_amdgcn_mfma_f32_32x32x16_bf16(af[mi], bf[ni], acc[mi][ni], 0, 0, 0);
      __builtin_amdgcn_s_setprio(0);
      if (p == 1 || p == 3) WAITV8();
      BAR();
    }
  }

  // Epilogue: C/D 32x32 layout: col=lane&31, row=(reg&3)+8*(reg>>2)+4*kh
  const int cbase = bn * 256 + wn * 64 + l31;
  const int rbase = bm * 256 + wm * 128 + (kh << 2);
  if (OUT32) {
    float* C = (float*)Cout;
    float bv[2];
#pragma unroll
    for (int ni = 0; ni < 2; ++ni) bv[ni] = bias[cbase + ni * 32];
#pragma unroll
    for (int mi = 0; mi < 4; ++mi)
#pragma unroll
      for (int ni = 0; ni < 2; ++ni)
#pragma unroll
        for (int reg = 0; reg < 16; ++reg) {
          const int row = rbase + mi * 32 + (reg & 3) + ((reg >> 2) << 3);
          C[(size_t)row * N + cbase + ni * 32] = acc[mi][ni][reg] + bv[ni];
        }
  } else {
    u16* C = (u16*)Cout;
#pragma unroll
    for (int mi = 0; mi < 4; ++mi)
#pragma unroll
      for (int ni = 0; ni < 2; ++ni)
#pragma unroll
        for (int reg = 0; reg < 16; ++reg) {
          const int row = rbase + mi * 32 + (reg & 3) + ((reg >> 2) << 3);
          C[(size_t)row * N + cbase + ni * 32] = f2bf(acc[mi][ni][reg]);
        }
  }
}
#undef UNIT

// ---------------------------------------------------------------------------
// RMSNorm + RoPE + scale fold for Q/K, V transpose to [H][D][S].
#define QSCALE (0.08838834764831845f * 1.4426950408889634f)  // 1/sqrt(128) * log2(e)

__global__ __launch_bounds__(256, 2) void qkv_prep(
    const u16* __restrict__ H, const float* __restrict__ cosb,
    const float* __restrict__ sinb, const float* __restrict__ nqw,
    const float* __restrict__ nkw, u16* __restrict__ Qo, u16* __restrict__ Ko,
    u16* __restrict__ Vo) {
  __shared__ u16 VT[128 * 72];
  const int head = blockIdx.y;
  const int t0 = blockIdx.x << 6;
  const int tid = threadIdx.x;
  const int tl = tid >> 2;
  const int db = (tid & 3) << 5;
  const int token = t0 + tl;

  const u16* hp = H + (size_t)token * 33792 + head * 128 + db;
  shortx8 qv[4], kvv[4], vv[4];
#pragma unroll
  for (int i = 0; i < 4; ++i) {
    qv[i] = *(const shortx8*)(hp + i * 8);
    kvv[i] = *(const shortx8*)(hp + 3072 + i * 8);
    vv[i] = *(const shortx8*)(hp + 6144 + i * 8);
  }
  float qx[32], kx[32];
  float sq = 0.f, sk = 0.f;
#pragma unroll
  for (int i = 0; i < 4; ++i)
#pragma unroll
    for (int j = 0; j < 8; ++j) {
      float a = bf2f((u16)qv[i][j]); qx[i * 8 + j] = a; sq += a * a;
      float b = bf2f((u16)kvv[i][j]); kx[i * 8 + j] = b; sk += b * b;
    }
  sq += __shfl_xor(sq, 1); sq += __shfl_xor(sq, 2);
  sk += __shfl_xor(sk, 1); sk += __shfl_xor(sk, 2);
  const float rq = rsqrtf(sq * (1.0f / 128.0f) + 1e-5f);
  const float rk = rsqrtf(sk * (1.0f / 128.0f) + 1e-5f);

  shortx8 oqv[4], okv[4];
#pragma unroll
  for (int p = 0; p < 16; ++p) {
    const float c = cosb[(size_t)token * 64 + (db >> 1) + p];
    const float s = sinb[(size_t)token * 64 + (db >> 1) + p];
    const int vi = p >> 2, vj = (p & 3) << 1;
    float a1 = qx[2 * p] * rq * nqw[db + 2 * p];
    float a2 = qx[2 * p + 1] * rq * nqw[db + 2 * p + 1];
    oqv[vi][vj] = (short)f2bf((a1 * c - a2 * s) * QSCALE);
    oqv[vi][vj + 1] = (short)f2bf((a2 * c + a1 * s) * QSCALE);
    float b1 = kx[2 * p] * rk * nkw[db + 2 * p];
    float b2 = kx[2 * p + 1] * rk * nkw[db + 2 * p + 1];
    okv[vi][vj] = (short)f2bf(b1 * c - b2 * s);
    okv[vi][vj + 1] = (short)f2bf(b2 * c + b1 * s);
  }
  {
    u16* qo = Qo + (size_t)head * 4096 * 128 + (size_t)token * 128 + db;
    u16* ko = Ko + (size_t)head * 4096 * 128 + (size_t)token * 128 + db;
#pragma unroll
    for (int i = 0; i < 4; ++i) {
      *(shortx8*)(qo + i * 8) = oqv[i];
      *(shortx8*)(ko + i * 8) = okv[i];
    }
  }
#pragma unroll
  for (int i = 0; i < 4; ++i)
#pragma unroll
    for (int j = 0; j < 8; ++j) VT[(db + i * 8 + j) * 72 + tl] = (u16)vv[i][j];
  __syncthreads();
#pragma unroll
  for (int ii = 0; ii < 4; ++ii) {
    const int chunk = tid + (ii << 8);
    const int d = chunk >> 3;
    const int j8 = (chunk & 7) << 3;
    shortx8 v = *(const shortx8*)(VT + d * 72 + j8);
    *(shortx8*)(Vo + (size_t)head * 128 * 4096 + (size_t)d * 4096 + t0 + j8) = v;
  }
}

// ---------------------------------------------------------------------------
// SiLU gate: CC[t][3072+j] = silu(m1)*m2
__global__ __launch_bounds__(256) void mlp_act(const u16* __restrict__ H,
                                               u16* __restrict__ CC) {
  const size_t id = (size_t)blockIdx.x * 256 + threadIdx.x;
  const int t = (int)(id / 1536);
  const int j = ((int)(id % 1536)) << 3;
  const u16* base = H + (size_t)t * 33792;
  shortx8 a = *(const shortx8*)(base + 9216 + j);
  shortx8 b = *(const shortx8*)(base + 21504 + j);
  shortx8 o;
#pragma unroll
  for (int e = 0; e < 8; ++e) {
    float x = bf2f((u16)a[e]);
    float y = bf2f((u16)b[e]);
    float sg = 1.0f / (1.0f + exp2f(-1.4426950408889634f * x));
    o[e] = (short)f2bf(x * sg * y);
  }
  *(shortx8*)(CC + (size_t)t * 15360 + 3072 + j) = o;
}

// ---------------------------------------------------------------------------
// Flash attention: grid (64 q-tiles, 24 heads), 4 waves x 16 q-rows, KV tile 64.
__global__ __launch_bounds__(256, 2) void attn_kernel(const u16* __restrict__ Qg,
                                                      const u16* __restrict__ Kg,
                                                      const u16* __restrict__ Vg,
                                                      u16* __restrict__ CC) {
  __shared__ u16 Ks[64 * 128];
  __shared__ u16 Vs[128 * 64];
  __shared__ u16 Ps[4 * 16 * 64];

  const int head = blockIdx.y;
  const int q0 = blockIdx.x << 6;
  const int tid = threadIdx.x;
  const int lane = tid & 63;
  const int wave = tid >> 6;
  const int l15 = lane & 15;
  const int l4 = lane >> 4;

  const u16* Qh = Qg + (size_t)head * 4096 * 128;
  const u16* Kh = Kg + (size_t)head * 4096 * 128;
  const u16* Vh = Vg + (size_t)head * 128 * 4096;

  shortx8 qf[4];
  {
    const u16* qp = Qh + (size_t)(q0 + wave * 16 + l15) * 128 + l4 * 8;
#pragma unroll
    for (int ks = 0; ks < 4; ++ks) qf[ks] = *(const shortx8*)(qp + ks * 32);
  }

  floatx4 o[8] = {};
  float mrun[4], lrun[4];
#pragma unroll
  for (int r = 0; r < 4; ++r) { mrun[r] = -1e30f; lrun[r] = 0.0f; }

  u16* Pw = Ps + wave * 1024;
  const int swz = l15 & 7;

  for (int s0 = 0; s0 < 4096; s0 += 64) {
    if (wave < 2) {
#pragma unroll
      for (int i = 0; i < 8; ++i) {
        const int c = wave * 8 + i;
        const int row = c * 4 + (lane >> 4);
        const int blk = (lane & 15) ^ (row & 7);
        __builtin_amdgcn_global_load_lds(GLB(Kh + (size_t)(s0 + row) * 128 + blk * 8),
                                         LDSC(Ks + c * 512), 16, 0, 0);
      }
    } else {
#pragma unroll
      for (int i = 0; i < 8; ++i) {
        const int cc = (wave - 2) * 8 + i;
        const int row = cc * 8 + (lane >> 3);
        const int blk = (lane & 7) ^ (row & 7);
        __builtin_amdgcn_global_load_lds(GLB(Vh + (size_t)row * 4096 + s0 + blk * 8),
                                         LDSC(Vs + cc * 512), 16, 0, 0);
      }
    }
    __syncthreads();

    floatx4 s[4] = {};
#pragma unroll
    for (int n = 0; n < 4; ++n) {
      const int krow = n * 16 + l15;
#pragma unroll
      for (int ks = 0; ks < 4; ++ks) {
        shortx8 kf = *(const shortx8*)(Ks + krow * 128 + (((ks * 4 + l4) ^ swz) << 3));
        s[n] = __builtin_amdgcn_mfma_f32_16x16x32_bf16(qf[ks], kf, s[n], 0, 0, 0);
      }
    }

    float alpha[4];
#pragma unroll
    for (int r = 0; r < 4; ++r) {
      float v = fmaxf(fmaxf(s[0][r], s[1][r]), fmaxf(s[2][r], s[3][r]));
      v = fmaxf(v, __shfl_xor(v, 1));
      v = fmaxf(v, __shfl_xor(v, 2));
      v = fmaxf(v, __shfl_xor(v, 4));
      v = fmaxf(v, __shfl_xor(v, 8));
      const float mn = fmaxf(mrun[r], v);
      alpha[r] = exp2f(mrun[r] - mn);
      mrun[r] = mn;
    }

    float rs[4] = {0.f, 0.f, 0.f, 0.f};
#pragma unroll
    for (int n = 0; n < 4; ++n) {
#pragma unroll
      for (int r = 0; r < 4; ++r) {
        const float p = exp2f(s[n][r] - mrun[r]);
        rs[r] += p;
        const int prow = (l4 << 2) + r;
        const int pblk = ((n << 1) + (l15 >> 3)) ^ (prow & 7);
        Pw[prow * 64 + (pblk << 3) + (l15 & 7)] = f2bf(p);
      }
    }
#pragma unroll
    for (int r = 0; r < 4; ++r) {
      float v = rs[r];
      v += __shfl_xor(v, 1);
      v += __shfl_xor(v, 2);
      v += __shfl_xor(v, 4);
      v += __shfl_xor(v, 8);
      lrun[r] = lrun[r] * alpha[r] + v;
    }
#pragma unroll
    for (int nd = 0; nd < 8; ++nd)
#pragma unroll
      for (int r = 0; r < 4; ++r) o[nd][r] *= alpha[r];

    shortx8 pf[2];
#pragma unroll
    for (int ks = 0; ks < 2; ++ks)
      pf[ks] = *(const shortx8*)(Pw + l15 * 64 + (((ks * 4 + l4) ^ swz) << 3));
#pragma unroll
    for (int nd = 0; nd < 8; ++nd) {
      const int vrow = nd * 16 + l15;
#pragma unroll
      for (int ks = 0; ks < 2; ++ks) {
        shortx8 vf = *(const shortx8*)(Vs + vrow * 64 + (((ks * 4 + l4) ^ swz) << 3));
        o[nd] = __builtin_amdgcn_mfma_f32_16x16x32_bf16(pf[ks], vf, o[nd], 0, 0, 0);
      }
    }
    __syncthreads();
  }

#pragma unroll
  for (int r = 0; r < 4; ++r) {
    const float inv = 1.0f / lrun[r];
    const int row = q0 + wave * 16 + (l4 << 2) + r;
    u16* outp = CC + (size_t)row * 15360 + head * 128 + l15;
#pragma unroll
    for (int nd = 0; nd < 8; ++nd) outp[nd << 4] = f2bf(o[nd][r] * inv);
  }
}

// ---------------------------------------------------------------------------
extern "C" void kernel_launch(void* const* d_in, const int* in_sizes, int n_in,
                              void* d_out, int out_size, void* d_ws, size_t ws_size,
                              hipStream_t stream) {
  const float* hs = (const float*)d_in[0];
  const float* cosb = (const float*)d_in[1];
  const float* sinb = (const float*)d_in[2];
  const float* w1 = (const float*)d_in[3];
  const float* wout = (const float*)d_in[4];
  const float* bout = (const float*)d_in[5];
  const float* nqw = (const float*)d_in[6];
  const float* nkw = (const float*)d_in[7];
  float* out = (float*)d_out;

  char* ws = (char*)d_ws;
  u16* X16 = (u16*)ws; ws += (size_t)4096 * 3072 * 2;
  u16* W1T = (u16*)ws; ws += (size_t)33792 * 3072 * 2;
  u16* WOT = (u16*)ws; ws += (size_t)3072 * 15360 * 2;
  u16* H   = (u16*)ws; ws += (size_t)4096 * 33792 * 2;
  u16* Qb  = (u16*)ws; ws += (size_t)24 * 4096 * 128 * 2;
  u16* Kb  = (u16*)ws; ws += (size_t)24 * 4096 * 128 * 2;
  u16* VTb = (u16*)ws; ws += (size_t)24 * 4096 * 128 * 2;
  u16* CC  = (u16*)ws; ws += (size_t)4096 * 15360 * 2;

  cast_bf16<<<6144, 256, 0, stream>>>(hs, X16);
  transpose_cast<<<(3072 / 64) * (33792 / 64), 256, 0, stream>>>(w1, W1T, 3072, 33792);
  transpose_cast<<<(15360 / 64) * (3072 / 64), 256, 0, stream>>>(wout, WOT, 15360, 3072);
  gemm8<0><<<(4096 / 256) * (33792 / 256), 512, 0, stream>>>(X16, W1T, H, nullptr,
                                                             4096, 33792, 3072);
  qkv_prep<<<dim3(64, 24), 256, 0, stream>>>(H, cosb, sinb, nqw, nkw, Qb, Kb, VTb);
  mlp_act<<<(4096 * 12288 / 8) / 256, 256, 0, stream>>>(H, CC);
  attn_kernel<<<dim3(64, 24), 256, 0, stream>>>(Qb, Kb, VTb, CC);
  gemm8<1><<<(4096 / 256) * (3072 / 256), 512, 0, stream>>>(CC, WOT, out, bout,
                                                            4096, 3072, 15360);
}

// Round 4
// 2027.786 us; speedup vs baseline: 1.0379x; 1.0379x over previous
//
#include <hip/hip_runtime.h>

typedef short shortx8 __attribute__((ext_vector_type(8)));   // 8 bf16 (4 VGPRs)
typedef float floatx4 __attribute__((ext_vector_type(4)));
typedef unsigned short u16;

#define GLB(x) ((const __attribute__((address_space(1))) void*)(x))
#define LDSC(x) ((__attribute__((address_space(3))) void*)(x))
#define BAR() asm volatile("s_barrier" ::: "memory")
#define WAITV8() asm volatile("s_waitcnt vmcnt(8)" ::: "memory")
#define WAITV0() asm volatile("s_waitcnt vmcnt(0)" ::: "memory")

__device__ __forceinline__ float bf2f(u16 u) {
  unsigned x = ((unsigned)u) << 16;
  float f;
  __builtin_memcpy(&f, &x, 4);
  return f;
}
__device__ __forceinline__ u16 f2bf(float f) {
  unsigned x;
  __builtin_memcpy(&x, &f, 4);
  x += 0x7fffu + ((x >> 16) & 1u);   // RNE
  return (u16)(x >> 16);
}

// ---------------------------------------------------------------------------
// fp32 -> bf16 flat cast (X)
__global__ __launch_bounds__(256) void cast_bf16(const float* __restrict__ src,
                                                 u16* __restrict__ dst) {
  const size_t i = ((size_t)blockIdx.x * 256 + threadIdx.x) << 3;
  floatx4 a = *(const floatx4*)(src + i);
  floatx4 b = *(const floatx4*)(src + i + 4);
  shortx8 o;
#pragma unroll
  for (int e = 0; e < 4; ++e) {
    o[e] = (short)f2bf(a[e]);
    o[e + 4] = (short)f2bf(b[e]);
  }
  *(shortx8*)(dst + i) = o;
}

// ---------------------------------------------------------------------------
// fp32 [R][C] -> bf16 [C][R] tile transpose+cast (64x64 tiles via LDS)
__global__ __launch_bounds__(256) void transpose_cast(const float* __restrict__ src,
                                                      u16* __restrict__ dst,
                                                      int R, int C) {
  __shared__ u16 T[64 * 72];
  const int tiles_c = C >> 6;
  const int r0 = (blockIdx.x / tiles_c) << 6;
  const int c0 = (blockIdx.x % tiles_c) << 6;
  const int tid = threadIdx.x;
  const int rl = tid >> 4;
  const int cb = (tid & 15) << 2;
#pragma unroll
  for (int rr = 0; rr < 4; ++rr) {
    const int row = rr * 16 + rl;
    floatx4 v = *(const floatx4*)(src + (size_t)(r0 + row) * C + c0 + cb);
#pragma unroll
    for (int i = 0; i < 4; ++i) T[(cb + i) * 72 + row] = f2bf(v[i]);
  }
  __syncthreads();
#pragma unroll
  for (int ii = 0; ii < 2; ++ii) {
    const int chunk = tid + (ii << 8);
    const int cr = chunk >> 3;
    const int r8 = (chunk & 7) << 3;
    shortx8 v = *(const shortx8*)(T + cr * 72 + r8);
    *(shortx8*)(dst + (size_t)(c0 + cr) * R + r0 + r8) = v;
  }
}

// ---------------------------------------------------------------------------
// 256x256 8-phase bf16 GEMM (R2 state, verified: 0 bank conflicts, ~982 TF).
// B^T layout: C = A[M][K] * B^T([N][K]).  16x16x32 MFMA.
// LDS: 2 buf x {A,B} x {k-slice0,k-slice1} units of [256 rows][32 k] (16KB).
// Read-side bank fix: 16B-block index XOR (row>>1)&3 via pre-swizzled global
// source + same XOR on ds_read.  4 phases/K-tile, 1 stage-unit/phase issued
// 1.5 tiles ahead, vmcnt(8) twice per tile, raw s_barrier, setprio.
template <int OUT32>
__global__ __launch_bounds__(512, 2) void gemm8(const u16* __restrict__ A,
                                                const u16* __restrict__ B,
                                                void* __restrict__ Cout,
                                                const float* __restrict__ bias,
                                                int M, int N, int K) {
  __shared__ u16 lds[8 * 8192];  // [buf][mat][ks][256*32] = 128 KiB

  const int nbm = M >> 8;
  const int nwg = nbm * (N >> 8);
  const int cpx = nwg >> 3;  // nwg % 8 == 0 for all our shapes
  const int wg = ((int)blockIdx.x & 7) * cpx + ((int)blockIdx.x >> 3);
  const int bm = wg % nbm;
  const int bn = wg / nbm;

  const int tid = threadIdx.x;
  const int lane = tid & 63;
  const int w = tid >> 6;        // 0..7
  const int wm = w >> 2;         // 0..1
  const int wn = w & 3;          // 0..3
  const int l15 = lane & 15;
  const int l4 = lane >> 4;
  const int NT = K >> 6;

  const int lrow = lane >> 2;    // staging: 0..15
  const int lblk = lane & 3;

#define UNIT(buf, mat, ks) (lds + (((buf) * 4 + (mat) * 2 + (ks)) << 13))

  const u16* Abase = A + (size_t)bm * 256 * K;
  const u16* Bbase = B + (size_t)bn * 256 * K;

  auto STAGE = [&](int mat, int ks, int buf, int t) {
    const u16* gb = mat ? Bbase : Abase;
#pragma unroll
    for (int j = 0; j < 2; ++j) {
      const int row = (w * 2 + j) * 16 + lrow;
      const int sblk = lblk ^ ((row >> 1) & 3);
      const u16* src = gb + (size_t)row * K + (t << 6) + (ks << 5) + (sblk << 3);
      __builtin_amdgcn_global_load_lds(GLB(src),
                                       LDSC(UNIT(buf, mat, ks) + ((w * 2 + j) << 9)),
                                       16, 0, 0);
    }
  };
  auto LDA = [&](int mf, int ks, int buf) -> shortx8 {
    const int row = wm * 128 + mf * 16 + l15;
    return *(const shortx8*)(UNIT(buf, 0, ks) + row * 32 + ((l4 ^ ((row >> 1) & 3)) << 3));
  };
  auto LDB = [&](int nf, int ks, int buf) -> shortx8 {
    const int row = wn * 64 + nf * 16 + l15;
    return *(const shortx8*)(UNIT(buf, 1, ks) + row * 32 + ((l4 ^ ((row >> 1) & 3)) << 3));
  };

  floatx4 acc[8][4] = {};

  // Prologue: tile0 all 4 units, tile1 k0 units (oldest-first).
  STAGE(0, 0, 0, 0); STAGE(1, 0, 0, 0);
  STAGE(0, 1, 0, 0); STAGE(1, 1, 0, 0);
  STAGE(0, 0, 1, 1); STAGE(1, 0, 1, 1);
  WAITV8();
  BAR();

  for (int T = 0; T < NT; ++T) {
    const int cur = T & 1, nxt = cur ^ 1;
    const int t1 = (T + 1 < NT) ? T + 1 : NT - 1;
    const int t2 = (T + 2 < NT) ? T + 2 : NT - 1;
    shortx8 af[4], bf[4];

    // ---- phase q0: C-half0 x k0;  stage A-k1 of tile T+1 -> buf nxt
#pragma unroll
    for (int m = 0; m < 4; ++m) af[m] = LDA(m, 0, cur);
#pragma unroll
    for (int n = 0; n < 4; ++n) bf[n] = LDB(n, 0, cur);
    STAGE(0, 1, nxt, t1);
    BAR();
    __builtin_amdgcn_s_setprio(1);
#pragma unroll
    for (int m = 0; m < 4; ++m)
#pragma unroll
      for (int n = 0; n < 4; ++n)
        acc[m][n] = __builtin_amdgcn_mfma_f32_16x16x32_bf16(af[m], bf[n], acc[m][n], 0, 0, 0);
    __builtin_amdgcn_s_setprio(0);
    BAR();

    // ---- phase q1: C-half1 x k0 (B-frags reused);  stage B-k1 of T+1
#pragma unroll
    for (int m = 0; m < 4; ++m) af[m] = LDA(4 + m, 0, cur);
    STAGE(1, 1, nxt, t1);
    BAR();
    __builtin_amdgcn_s_setprio(1);
#pragma unroll
    for (int m = 0; m < 4; ++m)
#pragma unroll
      for (int n = 0; n < 4; ++n)
        acc[4 + m][n] = __builtin_amdgcn_mfma_f32_16x16x32_bf16(af[m], bf[n], acc[4 + m][n], 0, 0, 0);
    __builtin_amdgcn_s_setprio(0);
    WAITV8();
    BAR();

    // ---- phase q2: C-half0 x k1;  stage A-k0 of tile T+2 -> buf cur
#pragma unroll
    for (int m = 0; m < 4; ++m) af[m] = LDA(m, 1, cur);
#pragma unroll
    for (int n = 0; n < 4; ++n) bf[n] = LDB(n, 1, cur);
    STAGE(0, 0, cur, t2);
    BAR();
    __builtin_amdgcn_s_setprio(1);
#pragma unroll
    for (int m = 0; m < 4; ++m)
#pragma unroll
      for (int n = 0; n < 4; ++n)
        acc[m][n] = __builtin_amdgcn_mfma_f32_16x16x32_bf16(af[m], bf[n], acc[m][n], 0, 0, 0);
    __builtin_amdgcn_s_setprio(0);
    BAR();

    // ---- phase q3: C-half1 x k1;  stage B-k0 of T+2
#pragma unroll
    for (int m = 0; m < 4; ++m) af[m] = LDA(4 + m, 1, cur);
    STAGE(1, 0, cur, t2);
    BAR();
    __builtin_amdgcn_s_setprio(1);
#pragma unroll
    for (int m = 0; m < 4; ++m)
#pragma unroll
      for (int n = 0; n < 4; ++n)
        acc[4 + m][n] = __builtin_amdgcn_mfma_f32_16x16x32_bf16(af[m], bf[n], acc[4 + m][n], 0, 0, 0);
    __builtin_amdgcn_s_setprio(0);
    WAITV8();
    BAR();
  }

  // Epilogue
  const int orow0 = bm * 256 + wm * 128 + (l4 << 2);
  const int ocol0 = bn * 256 + wn * 64 + l15;
  if (OUT32) {
    float* C = (float*)Cout;
    float bv[4];
#pragma unroll
    for (int n = 0; n < 4; ++n) bv[n] = bias[ocol0 + n * 16];
#pragma unroll
    for (int m = 0; m < 8; ++m)
#pragma unroll
      for (int n = 0; n < 4; ++n)
#pragma unroll
        for (int r = 0; r < 4; ++r)
          C[(size_t)(orow0 + m * 16 + r) * N + ocol0 + n * 16] = acc[m][n][r] + bv[n];
  } else {
    u16* C = (u16*)Cout;
#pragma unroll
    for (int m = 0; m < 8; ++m)
#pragma unroll
      for (int n = 0; n < 4; ++n)
#pragma unroll
        for (int r = 0; r < 4; ++r)
          C[(size_t)(orow0 + m * 16 + r) * N + ocol0 + n * 16] = f2bf(acc[m][n][r]);
  }
}
#undef UNIT

// ---------------------------------------------------------------------------
// RMSNorm + RoPE + scale fold for Q/K, V transpose to [H][D][S].
#define QSCALE (0.08838834764831845f * 1.4426950408889634f)  // 1/sqrt(128) * log2(e)

__global__ __launch_bounds__(256, 2) void qkv_prep(
    const u16* __restrict__ H, const float* __restrict__ cosb,
    const float* __restrict__ sinb, const float* __restrict__ nqw,
    const float* __restrict__ nkw, u16* __restrict__ Qo, u16* __restrict__ Ko,
    u16* __restrict__ Vo) {
  __shared__ u16 VT[128 * 72];
  const int head = blockIdx.y;
  const int t0 = blockIdx.x << 6;
  const int tid = threadIdx.x;
  const int tl = tid >> 2;
  const int db = (tid & 3) << 5;
  const int token = t0 + tl;

  const u16* hp = H + (size_t)token * 33792 + head * 128 + db;
  shortx8 qv[4], kvv[4], vv[4];
#pragma unroll
  for (int i = 0; i < 4; ++i) {
    qv[i] = *(const shortx8*)(hp + i * 8);
    kvv[i] = *(const shortx8*)(hp + 3072 + i * 8);
    vv[i] = *(const shortx8*)(hp + 6144 + i * 8);
  }
  float qx[32], kx[32];
  float sq = 0.f, sk = 0.f;
#pragma unroll
  for (int i = 0; i < 4; ++i)
#pragma unroll
    for (int j = 0; j < 8; ++j) {
      float a = bf2f((u16)qv[i][j]); qx[i * 8 + j] = a; sq += a * a;
      float b = bf2f((u16)kvv[i][j]); kx[i * 8 + j] = b; sk += b * b;
    }
  sq += __shfl_xor(sq, 1); sq += __shfl_xor(sq, 2);
  sk += __shfl_xor(sk, 1); sk += __shfl_xor(sk, 2);
  const float rq = rsqrtf(sq * (1.0f / 128.0f) + 1e-5f);
  const float rk = rsqrtf(sk * (1.0f / 128.0f) + 1e-5f);

  shortx8 oqv[4], okv[4];
#pragma unroll
  for (int p = 0; p < 16; ++p) {
    const float c = cosb[(size_t)token * 64 + (db >> 1) + p];
    const float s = sinb[(size_t)token * 64 + (db >> 1) + p];
    const int vi = p >> 2, vj = (p & 3) << 1;
    float a1 = qx[2 * p] * rq * nqw[db + 2 * p];
    float a2 = qx[2 * p + 1] * rq * nqw[db + 2 * p + 1];
    oqv[vi][vj] = (short)f2bf((a1 * c - a2 * s) * QSCALE);
    oqv[vi][vj + 1] = (short)f2bf((a2 * c + a1 * s) * QSCALE);
    float b1 = kx[2 * p] * rk * nkw[db + 2 * p];
    float b2 = kx[2 * p + 1] * rk * nkw[db + 2 * p + 1];
    okv[vi][vj] = (short)f2bf(b1 * c - b2 * s);
    okv[vi][vj + 1] = (short)f2bf(b2 * c + b1 * s);
  }
  {
    u16* qo = Qo + (size_t)head * 4096 * 128 + (size_t)token * 128 + db;
    u16* ko = Ko + (size_t)head * 4096 * 128 + (size_t)token * 128 + db;
#pragma unroll
    for (int i = 0; i < 4; ++i) {
      *(shortx8*)(qo + i * 8) = oqv[i];
      *(shortx8*)(ko + i * 8) = okv[i];
    }
  }
#pragma unroll
  for (int i = 0; i < 4; ++i)
#pragma unroll
    for (int j = 0; j < 8; ++j) VT[(db + i * 8 + j) * 72 + tl] = (u16)vv[i][j];
  __syncthreads();
#pragma unroll
  for (int ii = 0; ii < 4; ++ii) {
    const int chunk = tid + (ii << 8);
    const int d = chunk >> 3;
    const int j8 = (chunk & 7) << 3;
    shortx8 v = *(const shortx8*)(VT + d * 72 + j8);
    *(shortx8*)(Vo + (size_t)head * 128 * 4096 + (size_t)d * 4096 + t0 + j8) = v;
  }
}

// ---------------------------------------------------------------------------
// SiLU gate: CC[t][3072+j] = silu(m1)*m2
__global__ __launch_bounds__(256) void mlp_act(const u16* __restrict__ H,
                                               u16* __restrict__ CC) {
  const size_t id = (size_t)blockIdx.x * 256 + threadIdx.x;
  const int t = (int)(id / 1536);
  const int j = ((int)(id % 1536)) << 3;
  const u16* base = H + (size_t)t * 33792;
  shortx8 a = *(const shortx8*)(base + 9216 + j);
  shortx8 b = *(const shortx8*)(base + 21504 + j);
  shortx8 o;
#pragma unroll
  for (int e = 0; e < 8; ++e) {
    float x = bf2f((u16)a[e]);
    float y = bf2f((u16)b[e]);
    float sg = 1.0f / (1.0f + exp2f(-1.4426950408889634f * x));
    o[e] = (short)f2bf(x * sg * y);
  }
  *(shortx8*)(CC + (size_t)t * 15360 + 3072 + j) = o;
}

// ---------------------------------------------------------------------------
// Flash attention: grid (64 q-tiles, 24 heads), 4 waves x 16 q-rows, KV tile 64.
// Double-buffered K/V staging: all 4 waves stage both K and V slices (8 loads
// each), loop = {vmcnt(0) [issued one compute-phase ago -> near-free]; barrier;
// stage(next); compute(cur)}.  One barrier/iter; P is wave-private LDS.
__global__ __launch_bounds__(256, 2) void attn_kernel(const u16* __restrict__ Qg,
                                                      const u16* __restrict__ Kg,
                                                      const u16* __restrict__ Vg,
                                                      u16* __restrict__ CC) {
  __shared__ u16 Ks[2][64 * 128];   // [buf][kv][d] swizzled
  __shared__ u16 Vs[2][128 * 64];   // [buf][d][kv] swizzled
  __shared__ u16 Ps[4 * 16 * 64];

  const int head = blockIdx.y;
  const int q0 = blockIdx.x << 6;
  const int tid = threadIdx.x;
  const int lane = tid & 63;
  const int wave = tid >> 6;
  const int l15 = lane & 15;
  const int l4 = lane >> 4;

  const u16* Qh = Qg + (size_t)head * 4096 * 128;
  const u16* Kh = Kg + (size_t)head * 4096 * 128;
  const u16* Vh = Vg + (size_t)head * 128 * 4096;

  auto STAGE_KV = [&](int s0, int buf) {
#pragma unroll
    for (int i = 0; i < 4; ++i) {            // K: chunk = 4 rows of [64][128]
      const int c = wave * 4 + i;
      const int row = c * 4 + (lane >> 4);
      const int blk = (lane & 15) ^ (row & 7);
      __builtin_amdgcn_global_load_lds(GLB(Kh + (size_t)(s0 + row) * 128 + blk * 8),
                                       LDSC(&Ks[buf][c * 512]), 16, 0, 0);
    }
#pragma unroll
    for (int i = 0; i < 4; ++i) {            // V: chunk = 8 rows of [128][64]
      const int cc = wave * 4 + i;
      const int row = cc * 8 + (lane >> 3);
      const int blk = (lane & 7) ^ (row & 7);
      __builtin_amdgcn_global_load_lds(GLB(Vh + (size_t)row * 4096 + s0 + blk * 8),
                                       LDSC(&Vs[buf][cc * 512]), 16, 0, 0);
    }
  };

  shortx8 qf[4];
  {
    const u16* qp = Qh + (size_t)(q0 + wave * 16 + l15) * 128 + l4 * 8;
#pragma unroll
    for (int ks = 0; ks < 4; ++ks) qf[ks] = *(const shortx8*)(qp + ks * 32);
  }

  floatx4 o[8] = {};
  float mrun[4], lrun[4];
#pragma unroll
  for (int r = 0; r < 4; ++r) { mrun[r] = -1e30f; lrun[r] = 0.0f; }

  u16* Pw = Ps + wave * 1024;
  const int swz = l15 & 7;

  STAGE_KV(0, 0);

  for (int it = 0; it < 64; ++it) {
    const int cur = it & 1;
    WAITV0();   // own 8 loads of tile `it` (issued one compute-phase ago)
    BAR();      // rendezvous: all waves' tile-`it` slices complete
    if (it < 63) STAGE_KV((it + 1) << 6, cur ^ 1);

    // S = Q K^T (scaled via Q), rows 4*l4+r, cols n*16+l15
    floatx4 s[4] = {};
    __builtin_amdgcn_s_setprio(1);
#pragma unroll
    for (int n = 0; n < 4; ++n) {
      const int krow = n * 16 + l15;
#pragma unroll
      for (int ks = 0; ks < 4; ++ks) {
        shortx8 kf = *(const shortx8*)(&Ks[cur][krow * 128 + (((ks * 4 + l4) ^ swz) << 3)]);
        s[n] = __builtin_amdgcn_mfma_f32_16x16x32_bf16(qf[ks], kf, s[n], 0, 0, 0);
      }
    }
    __builtin_amdgcn_s_setprio(0);

    float alpha[4];
#pragma unroll
    for (int r = 0; r < 4; ++r) {
      float v = fmaxf(fmaxf(s[0][r], s[1][r]), fmaxf(s[2][r], s[3][r]));
      v = fmaxf(v, __shfl_xor(v, 1));
      v = fmaxf(v, __shfl_xor(v, 2));
      v = fmaxf(v, __shfl_xor(v, 4));
      v = fmaxf(v, __shfl_xor(v, 8));
      const float mn = fmaxf(mrun[r], v);
      alpha[r] = exp2f(mrun[r] - mn);
      mrun[r] = mn;
    }

    float rs[4] = {0.f, 0.f, 0.f, 0.f};
#pragma unroll
    for (int n = 0; n < 4; ++n) {
#pragma unroll
      for (int r = 0; r < 4; ++r) {
        const float p = exp2f(s[n][r] - mrun[r]);
        rs[r] += p;
        const int prow = (l4 << 2) + r;
        const int pblk = ((n << 1) + (l15 >> 3)) ^ (prow & 7);
        Pw[prow * 64 + (pblk << 3) + (l15 & 7)] = f2bf(p);
      }
    }
#pragma unroll
    for (int r = 0; r < 4; ++r) {
      float v = rs[r];
      v += __shfl_xor(v, 1);
      v += __shfl_xor(v, 2);
      v += __shfl_xor(v, 4);
      v += __shfl_xor(v, 8);
      lrun[r] = lrun[r] * alpha[r] + v;
    }
#pragma unroll
    for (int nd = 0; nd < 8; ++nd)
#pragma unroll
      for (int r = 0; r < 4; ++r) o[nd][r] *= alpha[r];

    // O += P V   (P wave-private: compiler lgkmcnt orders write->read)
    shortx8 pf[2];
#pragma unroll
    for (int ks = 0; ks < 2; ++ks)
      pf[ks] = *(const shortx8*)(Pw + l15 * 64 + (((ks * 4 + l4) ^ swz) << 3));
    __builtin_amdgcn_s_setprio(1);
#pragma unroll
    for (int nd = 0; nd < 8; ++nd) {
      const int vrow = nd * 16 + l15;
#pragma unroll
      for (int ks = 0; ks < 2; ++ks) {
        shortx8 vf = *(const shortx8*)(&Vs[cur][vrow * 64 + (((ks * 4 + l4) ^ swz) << 3)]);
        o[nd] = __builtin_amdgcn_mfma_f32_16x16x32_bf16(pf[ks], vf, o[nd], 0, 0, 0);
      }
    }
    __builtin_amdgcn_s_setprio(0);
  }

#pragma unroll
  for (int r = 0; r < 4; ++r) {
    const float inv = 1.0f / lrun[r];
    const int row = q0 + wave * 16 + (l4 << 2) + r;
    u16* outp = CC + (size_t)row * 15360 + head * 128 + l15;
#pragma unroll
    for (int nd = 0; nd < 8; ++nd) outp[nd << 4] = f2bf(o[nd][r] * inv);
  }
}

// ---------------------------------------------------------------------------
extern "C" void kernel_launch(void* const* d_in, const int* in_sizes, int n_in,
                              void* d_out, int out_size, void* d_ws, size_t ws_size,
                              hipStream_t stream) {
  const float* hs = (const float*)d_in[0];
  const float* cosb = (const float*)d_in[1];
  const float* sinb = (const float*)d_in[2];
  const float* w1 = (const float*)d_in[3];
  const float* wout = (const float*)d_in[4];
  const float* bout = (const float*)d_in[5];
  const float* nqw = (const float*)d_in[6];
  const float* nkw = (const float*)d_in[7];
  float* out = (float*)d_out;

  char* ws = (char*)d_ws;
  u16* X16 = (u16*)ws; ws += (size_t)4096 * 3072 * 2;
  u16* W1T = (u16*)ws; ws += (size_t)33792 * 3072 * 2;
  u16* WOT = (u16*)ws; ws += (size_t)3072 * 15360 * 2;
  u16* H   = (u16*)ws; ws += (size_t)4096 * 33792 * 2;
  u16* Qb  = (u16*)ws; ws += (size_t)24 * 4096 * 128 * 2;
  u16* Kb  = (u16*)ws; ws += (size_t)24 * 4096 * 128 * 2;
  u16* VTb = (u16*)ws; ws += (size_t)24 * 4096 * 128 * 2;
  u16* CC  = (u16*)ws; ws += (size_t)4096 * 15360 * 2;

  cast_bf16<<<6144, 256, 0, stream>>>(hs, X16);
  transpose_cast<<<(3072 / 64) * (33792 / 64), 256, 0, stream>>>(w1, W1T, 3072, 33792);
  transpose_cast<<<(15360 / 64) * (3072 / 64), 256, 0, stream>>>(wout, WOT, 15360, 3072);
  gemm8<0><<<(4096 / 256) * (33792 / 256), 512, 0, stream>>>(X16, W1T, H, nullptr,
                                                             4096, 33792, 3072);
  qkv_prep<<<dim3(64, 24), 256, 0, stream>>>(H, cosb, sinb, nqw, nkw, Qb, Kb, VTb);
  mlp_act<<<(4096 * 12288 / 8) / 256, 256, 0, stream>>>(H, CC);
  attn_kernel<<<dim3(64, 24), 256, 0, stream>>>(Qb, Kb, VTb, CC);
  gemm8<1><<<(4096 / 256) * (3072 / 256), 512, 0, stream>>>(CC, WOT, out, bout,
                                                            4096, 3072, 15360);
}

// Round 5
// 2001.105 us; speedup vs baseline: 1.0517x; 1.0133x over previous
//
#include <hip/hip_runtime.h>

typedef short shortx8 __attribute__((ext_vector_type(8)));   // 8 bf16 (4 VGPRs)
typedef float floatx4 __attribute__((ext_vector_type(4)));
typedef unsigned short u16;

#define GLB(x) ((const __attribute__((address_space(1))) void*)(x))
#define LDSC(x) ((__attribute__((address_space(3))) void*)(x))
#define BAR() asm volatile("s_barrier" ::: "memory")
#define WAITV8() asm volatile("s_waitcnt vmcnt(8)" ::: "memory")

__device__ __forceinline__ float bf2f(u16 u) {
  unsigned x = ((unsigned)u) << 16;
  float f;
  __builtin_memcpy(&f, &x, 4);
  return f;
}
__device__ __forceinline__ u16 f2bf(float f) {
  unsigned x;
  __builtin_memcpy(&x, &f, 4);
  x += 0x7fffu + ((x >> 16) & 1u);   // RNE
  return (u16)(x >> 16);
}

// ---------------------------------------------------------------------------
// fp32 -> bf16 flat cast (X)
__global__ __launch_bounds__(256) void cast_bf16(const float* __restrict__ src,
                                                 u16* __restrict__ dst) {
  const size_t i = ((size_t)blockIdx.x * 256 + threadIdx.x) << 3;
  floatx4 a = *(const floatx4*)(src + i);
  floatx4 b = *(const floatx4*)(src + i + 4);
  shortx8 o;
#pragma unroll
  for (int e = 0; e < 4; ++e) {
    o[e] = (short)f2bf(a[e]);
    o[e + 4] = (short)f2bf(b[e]);
  }
  *(shortx8*)(dst + i) = o;
}

// ---------------------------------------------------------------------------
// fp32 [R][C] -> bf16 [C][R] tile transpose+cast (64x64 tiles via LDS)
__global__ __launch_bounds__(256) void transpose_cast(const float* __restrict__ src,
                                                      u16* __restrict__ dst,
                                                      int R, int C) {
  __shared__ u16 T[64 * 72];
  const int tiles_c = C >> 6;
  const int r0 = (blockIdx.x / tiles_c) << 6;
  const int c0 = (blockIdx.x % tiles_c) << 6;
  const int tid = threadIdx.x;
  const int rl = tid >> 4;
  const int cb = (tid & 15) << 2;
#pragma unroll
  for (int rr = 0; rr < 4; ++rr) {
    const int row = rr * 16 + rl;
    floatx4 v = *(const floatx4*)(src + (size_t)(r0 + row) * C + c0 + cb);
#pragma unroll
    for (int i = 0; i < 4; ++i) T[(cb + i) * 72 + row] = f2bf(v[i]);
  }
  __syncthreads();
#pragma unroll
  for (int ii = 0; ii < 2; ++ii) {
    const int chunk = tid + (ii << 8);
    const int cr = chunk >> 3;
    const int r8 = (chunk & 7) << 3;
    shortx8 v = *(const shortx8*)(T + cr * 72 + r8);
    *(shortx8*)(dst + (size_t)(c0 + cr) * R + r0 + r8) = v;
  }
}

// ---------------------------------------------------------------------------
// 256x256 8-phase bf16 GEMM (R2 schedule: 0 bank conflicts, ~982 TF).
// B^T layout: C = A[M][K-chunk] * B^T([N][K-chunk]).  16x16x32 MFMA.
// MODE 0: bf16 C, full K.  MODE 1: fp32 partial (no bias), split-K chunk
// selected by blockIdx.y (chunk length Ksub, partial c at Cout + y*M*N).
template <int MODE>
__global__ __launch_bounds__(512, 2) void gemm8(const u16* __restrict__ A,
                                                const u16* __restrict__ B,
                                                void* __restrict__ Cout,
                                                int M, int N, int K, int Ksub) {
  __shared__ u16 lds[8 * 8192];  // [buf][mat][ks][256*32] = 128 KiB

  const int nbm = M >> 8;
  const int nwg = nbm * (N >> 8);
  const int cpx = nwg >> 3;  // nwg % 8 == 0 for all our shapes
  const int wg = ((int)blockIdx.x & 7) * cpx + ((int)blockIdx.x >> 3);
  const int bm = wg % nbm;
  const int bn = wg / nbm;
  const int koff = (int)blockIdx.y * Ksub;

  const int tid = threadIdx.x;
  const int lane = tid & 63;
  const int w = tid >> 6;        // 0..7
  const int wm = w >> 2;         // 0..1
  const int wn = w & 3;          // 0..3
  const int l15 = lane & 15;
  const int l4 = lane >> 4;
  const int NT = Ksub >> 6;

  const int lrow = lane >> 2;    // staging: 0..15
  const int lblk = lane & 3;

#define UNIT(buf, mat, ks) (lds + (((buf) * 4 + (mat) * 2 + (ks)) << 13))

  const u16* Abase = A + (size_t)bm * 256 * K + koff;
  const u16* Bbase = B + (size_t)bn * 256 * K + koff;

  auto STAGE = [&](int mat, int ks, int buf, int t) {
    const u16* gb = mat ? Bbase : Abase;
#pragma unroll
    for (int j = 0; j < 2; ++j) {
      const int row = (w * 2 + j) * 16 + lrow;
      const int sblk = lblk ^ ((row >> 1) & 3);
      const u16* src = gb + (size_t)row * K + (t << 6) + (ks << 5) + (sblk << 3);
      __builtin_amdgcn_global_load_lds(GLB(src),
                                       LDSC(UNIT(buf, mat, ks) + ((w * 2 + j) << 9)),
                                       16, 0, 0);
    }
  };
  auto LDA = [&](int mf, int ks, int buf) -> shortx8 {
    const int row = wm * 128 + mf * 16 + l15;
    return *(const shortx8*)(UNIT(buf, 0, ks) + row * 32 + ((l4 ^ ((row >> 1) & 3)) << 3));
  };
  auto LDB = [&](int nf, int ks, int buf) -> shortx8 {
    const int row = wn * 64 + nf * 16 + l15;
    return *(const shortx8*)(UNIT(buf, 1, ks) + row * 32 + ((l4 ^ ((row >> 1) & 3)) << 3));
  };

  floatx4 acc[8][4] = {};

  // Prologue: tile0 all 4 units, tile1 k0 units (oldest-first).
  STAGE(0, 0, 0, 0); STAGE(1, 0, 0, 0);
  STAGE(0, 1, 0, 0); STAGE(1, 1, 0, 0);
  STAGE(0, 0, 1, 1); STAGE(1, 0, 1, 1);
  WAITV8();
  BAR();

  for (int T = 0; T < NT; ++T) {
    const int cur = T & 1, nxt = cur ^ 1;
    const int t1 = (T + 1 < NT) ? T + 1 : NT - 1;
    const int t2 = (T + 2 < NT) ? T + 2 : NT - 1;
    shortx8 af[4], bf[4];

    // ---- phase q0: C-half0 x k0;  stage A-k1 of tile T+1 -> buf nxt
#pragma unroll
    for (int m = 0; m < 4; ++m) af[m] = LDA(m, 0, cur);
#pragma unroll
    for (int n = 0; n < 4; ++n) bf[n] = LDB(n, 0, cur);
    STAGE(0, 1, nxt, t1);
    BAR();
    __builtin_amdgcn_s_setprio(1);
#pragma unroll
    for (int m = 0; m < 4; ++m)
#pragma unroll
      for (int n = 0; n < 4; ++n)
        acc[m][n] = __builtin_amdgcn_mfma_f32_16x16x32_bf16(af[m], bf[n], acc[m][n], 0, 0, 0);
    __builtin_amdgcn_s_setprio(0);
    BAR();

    // ---- phase q1: C-half1 x k0 (B-frags reused);  stage B-k1 of T+1
#pragma unroll
    for (int m = 0; m < 4; ++m) af[m] = LDA(4 + m, 0, cur);
    STAGE(1, 1, nxt, t1);
    BAR();
    __builtin_amdgcn_s_setprio(1);
#pragma unroll
    for (int m = 0; m < 4; ++m)
#pragma unroll
      for (int n = 0; n < 4; ++n)
        acc[4 + m][n] = __builtin_amdgcn_mfma_f32_16x16x32_bf16(af[m], bf[n], acc[4 + m][n], 0, 0, 0);
    __builtin_amdgcn_s_setprio(0);
    WAITV8();
    BAR();

    // ---- phase q2: C-half0 x k1;  stage A-k0 of tile T+2 -> buf cur
#pragma unroll
    for (int m = 0; m < 4; ++m) af[m] = LDA(m, 1, cur);
#pragma unroll
    for (int n = 0; n < 4; ++n) bf[n] = LDB(n, 1, cur);
    STAGE(0, 0, cur, t2);
    BAR();
    __builtin_amdgcn_s_setprio(1);
#pragma unroll
    for (int m = 0; m < 4; ++m)
#pragma unroll
      for (int n = 0; n < 4; ++n)
        acc[m][n] = __builtin_amdgcn_mfma_f32_16x16x32_bf16(af[m], bf[n], acc[m][n], 0, 0, 0);
    __builtin_amdgcn_s_setprio(0);
    BAR();

    // ---- phase q3: C-half1 x k1;  stage B-k0 of T+2
#pragma unroll
    for (int m = 0; m < 4; ++m) af[m] = LDA(4 + m, 1, cur);
    STAGE(1, 0, cur, t2);
    BAR();
    __builtin_amdgcn_s_setprio(1);
#pragma unroll
    for (int m = 0; m < 4; ++m)
#pragma unroll
      for (int n = 0; n < 4; ++n)
        acc[4 + m][n] = __builtin_amdgcn_mfma_f32_16x16x32_bf16(af[m], bf[n], acc[4 + m][n], 0, 0, 0);
    __builtin_amdgcn_s_setprio(0);
    WAITV8();
    BAR();
  }

  // Epilogue
  const int orow0 = bm * 256 + wm * 128 + (l4 << 2);
  const int ocol0 = bn * 256 + wn * 64 + l15;
  if (MODE == 0) {
    u16* C = (u16*)Cout;
#pragma unroll
    for (int m = 0; m < 8; ++m)
#pragma unroll
      for (int n = 0; n < 4; ++n)
#pragma unroll
        for (int r = 0; r < 4; ++r)
          C[(size_t)(orow0 + m * 16 + r) * N + ocol0 + n * 16] = f2bf(acc[m][n][r]);
  } else {
    float* C = (float*)Cout + (size_t)blockIdx.y * M * N;
#pragma unroll
    for (int m = 0; m < 8; ++m)
#pragma unroll
      for (int n = 0; n < 4; ++n)
#pragma unroll
        for (int r = 0; r < 4; ++r)
          C[(size_t)(orow0 + m * 16 + r) * N + ocol0 + n * 16] = acc[m][n][r];
  }
}
#undef UNIT

// ---------------------------------------------------------------------------
// Split-K reduction: out = p0+p1+p2+p3 + bias
__global__ __launch_bounds__(256) void reduce_bias(const float* __restrict__ P,
                                                   const float* __restrict__ bias,
                                                   float* __restrict__ out) {
  const size_t base = ((size_t)blockIdx.x * 256 + threadIdx.x) << 2;
  const size_t stride = (size_t)4096 * 3072;
  floatx4 a = *(const floatx4*)(P + base);
  floatx4 b = *(const floatx4*)(P + stride + base);
  floatx4 c = *(const floatx4*)(P + 2 * stride + base);
  floatx4 d = *(const floatx4*)(P + 3 * stride + base);
  floatx4 bb = *(const floatx4*)(bias + (base % 3072));
  *(floatx4*)(out + base) = a + b + c + d + bb;
}

// ---------------------------------------------------------------------------
// RMSNorm + RoPE + scale fold for Q/K, V transpose to [H][D][S].
#define QSCALE (0.08838834764831845f * 1.4426950408889634f)  // 1/sqrt(128) * log2(e)

__global__ __launch_bounds__(256, 2) void qkv_prep(
    const u16* __restrict__ H, const float* __restrict__ cosb,
    const float* __restrict__ sinb, const float* __restrict__ nqw,
    const float* __restrict__ nkw, u16* __restrict__ Qo, u16* __restrict__ Ko,
    u16* __restrict__ Vo) {
  __shared__ u16 VT[128 * 72];
  const int head = blockIdx.y;
  const int t0 = blockIdx.x << 6;
  const int tid = threadIdx.x;
  const int tl = tid >> 2;
  const int db = (tid & 3) << 5;
  const int token = t0 + tl;

  const u16* hp = H + (size_t)token * 33792 + head * 128 + db;
  shortx8 qv[4], kvv[4], vv[4];
#pragma unroll
  for (int i = 0; i < 4; ++i) {
    qv[i] = *(const shortx8*)(hp + i * 8);
    kvv[i] = *(const shortx8*)(hp + 3072 + i * 8);
    vv[i] = *(const shortx8*)(hp + 6144 + i * 8);
  }
  float qx[32], kx[32];
  float sq = 0.f, sk = 0.f;
#pragma unroll
  for (int i = 0; i < 4; ++i)
#pragma unroll
    for (int j = 0; j < 8; ++j) {
      float a = bf2f((u16)qv[i][j]); qx[i * 8 + j] = a; sq += a * a;
      float b = bf2f((u16)kvv[i][j]); kx[i * 8 + j] = b; sk += b * b;
    }
  sq += __shfl_xor(sq, 1); sq += __shfl_xor(sq, 2);
  sk += __shfl_xor(sk, 1); sk += __shfl_xor(sk, 2);
  const float rq = rsqrtf(sq * (1.0f / 128.0f) + 1e-5f);
  const float rk = rsqrtf(sk * (1.0f / 128.0f) + 1e-5f);

  shortx8 oqv[4], okv[4];
#pragma unroll
  for (int p = 0; p < 16; ++p) {
    const float c = cosb[(size_t)token * 64 + (db >> 1) + p];
    const float s = sinb[(size_t)token * 64 + (db >> 1) + p];
    const int vi = p >> 2, vj = (p & 3) << 1;
    float a1 = qx[2 * p] * rq * nqw[db + 2 * p];
    float a2 = qx[2 * p + 1] * rq * nqw[db + 2 * p + 1];
    oqv[vi][vj] = (short)f2bf((a1 * c - a2 * s) * QSCALE);
    oqv[vi][vj + 1] = (short)f2bf((a2 * c + a1 * s) * QSCALE);
    float b1 = kx[2 * p] * rk * nkw[db + 2 * p];
    float b2 = kx[2 * p + 1] * rk * nkw[db + 2 * p + 1];
    okv[vi][vj] = (short)f2bf(b1 * c - b2 * s);
    okv[vi][vj + 1] = (short)f2bf(b2 * c + b1 * s);
  }
  {
    u16* qo = Qo + (size_t)head * 4096 * 128 + (size_t)token * 128 + db;
    u16* ko = Ko + (size_t)head * 4096 * 128 + (size_t)token * 128 + db;
#pragma unroll
    for (int i = 0; i < 4; ++i) {
      *(shortx8*)(qo + i * 8) = oqv[i];
      *(shortx8*)(ko + i * 8) = okv[i];
    }
  }
#pragma unroll
  for (int i = 0; i < 4; ++i)
#pragma unroll
    for (int j = 0; j < 8; ++j) VT[(db + i * 8 + j) * 72 + tl] = (u16)vv[i][j];
  __syncthreads();
#pragma unroll
  for (int ii = 0; ii < 4; ++ii) {
    const int chunk = tid + (ii << 8);
    const int d = chunk >> 3;
    const int j8 = (chunk & 7) << 3;
    shortx8 v = *(const shortx8*)(VT + d * 72 + j8);
    *(shortx8*)(Vo + (size_t)head * 128 * 4096 + (size_t)d * 4096 + t0 + j8) = v;
  }
}

// ---------------------------------------------------------------------------
// SiLU gate: CC[t][3072+j] = silu(m1)*m2
__global__ __launch_bounds__(256) void mlp_act(const u16* __restrict__ H,
                                               u16* __restrict__ CC) {
  const size_t id = (size_t)blockIdx.x * 256 + threadIdx.x;
  const int t = (int)(id / 1536);
  const int j = ((int)(id % 1536)) << 3;
  const u16* base = H + (size_t)t * 33792;
  shortx8 a = *(const shortx8*)(base + 9216 + j);
  shortx8 b = *(const shortx8*)(base + 21504 + j);
  shortx8 o;
#pragma unroll
  for (int e = 0; e < 8; ++e) {
    float x = bf2f((u16)a[e]);
    float y = bf2f((u16)b[e]);
    float sg = 1.0f / (1.0f + exp2f(-1.4426950408889634f * x));
    o[e] = (short)f2bf(x * sg * y);
  }
  *(shortx8*)(CC + (size_t)t * 15360 + 3072 + j) = o;
}

// ---------------------------------------------------------------------------
// Flash attention (R2-measured structure): grid (64 q-tiles, 24 heads),
// 4 waves x 16 q-rows, KV tile 64.  K/V/P LDS XOR-swizzled; K/V staged with
// pre-swizzled global source + linear global_load_lds dest.
// Added: lossless defer-rescale (skip O-scale pass when all alpha == 1).
__global__ __launch_bounds__(256, 2) void attn_kernel(const u16* __restrict__ Qg,
                                                      const u16* __restrict__ Kg,
                                                      const u16* __restrict__ Vg,
                                                      u16* __restrict__ CC) {
  __shared__ u16 Ks[64 * 128];
  __shared__ u16 Vs[128 * 64];
  __shared__ u16 Ps[4 * 16 * 64];

  const int head = blockIdx.y;
  const int q0 = blockIdx.x << 6;
  const int tid = threadIdx.x;
  const int lane = tid & 63;
  const int wave = tid >> 6;
  const int l15 = lane & 15;
  const int l4 = lane >> 4;

  const u16* Qh = Qg + (size_t)head * 4096 * 128;
  const u16* Kh = Kg + (size_t)head * 4096 * 128;
  const u16* Vh = Vg + (size_t)head * 128 * 4096;

  shortx8 qf[4];
  {
    const u16* qp = Qh + (size_t)(q0 + wave * 16 + l15) * 128 + l4 * 8;
#pragma unroll
    for (int ks = 0; ks < 4; ++ks) qf[ks] = *(const shortx8*)(qp + ks * 32);
  }

  floatx4 o[8] = {};
  float mrun[4], lrun[4];
#pragma unroll
  for (int r = 0; r < 4; ++r) { mrun[r] = -1e30f; lrun[r] = 0.0f; }

  u16* Pw = Ps + wave * 1024;
  const int swz = l15 & 7;

  for (int s0 = 0; s0 < 4096; s0 += 64) {
    if (wave < 2) {
#pragma unroll
      for (int i = 0; i < 8; ++i) {
        const int c = wave * 8 + i;
        const int row = c * 4 + (lane >> 4);
        const int blk = (lane & 15) ^ (row & 7);
        __builtin_amdgcn_global_load_lds(GLB(Kh + (size_t)(s0 + row) * 128 + blk * 8),
                                         LDSC(Ks + c * 512), 16, 0, 0);
      }
    } else {
#pragma unroll
      for (int i = 0; i < 8; ++i) {
        const int cc = (wave - 2) * 8 + i;
        const int row = cc * 8 + (lane >> 3);
        const int blk = (lane & 7) ^ (row & 7);
        __builtin_amdgcn_global_load_lds(GLB(Vh + (size_t)row * 4096 + s0 + blk * 8),
                                         LDSC(Vs + cc * 512), 16, 0, 0);
      }
    }
    __syncthreads();

    floatx4 s[4] = {};
#pragma unroll
    for (int n = 0; n < 4; ++n) {
      const int krow = n * 16 + l15;
#pragma unroll
      for (int ks = 0; ks < 4; ++ks) {
        shortx8 kf = *(const shortx8*)(Ks + krow * 128 + (((ks * 4 + l4) ^ swz) << 3));
        s[n] = __builtin_amdgcn_mfma_f32_16x16x32_bf16(qf[ks], kf, s[n], 0, 0, 0);
      }
    }

    float alpha[4];
#pragma unroll
    for (int r = 0; r < 4; ++r) {
      float v = fmaxf(fmaxf(s[0][r], s[1][r]), fmaxf(s[2][r], s[3][r]));
      v = fmaxf(v, __shfl_xor(v, 1));
      v = fmaxf(v, __shfl_xor(v, 2));
      v = fmaxf(v, __shfl_xor(v, 4));
      v = fmaxf(v, __shfl_xor(v, 8));
      const float mn = fmaxf(mrun[r], v);
      alpha[r] = exp2f(mrun[r] - mn);
      mrun[r] = mn;
    }

    float rs[4] = {0.f, 0.f, 0.f, 0.f};
#pragma unroll
    for (int n = 0; n < 4; ++n) {
#pragma unroll
      for (int r = 0; r < 4; ++r) {
        const float p = exp2f(s[n][r] - mrun[r]);
        rs[r] += p;
        const int prow = (l4 << 2) + r;
        const int pblk = ((n << 1) + (l15 >> 3)) ^ (prow & 7);
        Pw[prow * 64 + (pblk << 3) + (l15 & 7)] = f2bf(p);
      }
    }
#pragma unroll
    for (int r = 0; r < 4; ++r) {
      float v = rs[r];
      v += __shfl_xor(v, 1);
      v += __shfl_xor(v, 2);
      v += __shfl_xor(v, 4);
      v += __shfl_xor(v, 8);
      lrun[r] = lrun[r] * alpha[r] + v;
    }
    // Lossless defer-rescale: when no lane's max advanced, every alpha is
    // exactly 1.0f -> the 32-mult O-rescale is a no-op; skip it (wave-uniform).
    if (__any((alpha[0] < 1.0f) || (alpha[1] < 1.0f) ||
              (alpha[2] < 1.0f) || (alpha[3] < 1.0f))) {
#pragma unroll
      for (int nd = 0; nd < 8; ++nd)
#pragma unroll
        for (int r = 0; r < 4; ++r) o[nd][r] *= alpha[r];
    }

    shortx8 pf[2];
#pragma unroll
    for (int ks = 0; ks < 2; ++ks)
      pf[ks] = *(const shortx8*)(Pw + l15 * 64 + (((ks * 4 + l4) ^ swz) << 3));
#pragma unroll
    for (int nd = 0; nd < 8; ++nd) {
      const int vrow = nd * 16 + l15;
#pragma unroll
      for (int ks = 0; ks < 2; ++ks) {
        shortx8 vf = *(const shortx8*)(Vs + vrow * 64 + (((ks * 4 + l4) ^ swz) << 3));
        o[nd] = __builtin_amdgcn_mfma_f32_16x16x32_bf16(pf[ks], vf, o[nd], 0, 0, 0);
      }
    }
    __syncthreads();
  }

#pragma unroll
  for (int r = 0; r < 4; ++r) {
    const float inv = 1.0f / lrun[r];
    const int row = q0 + wave * 16 + (l4 << 2) + r;
    u16* outp = CC + (size_t)row * 15360 + head * 128 + l15;
#pragma unroll
    for (int nd = 0; nd < 8; ++nd) outp[nd << 4] = f2bf(o[nd][r] * inv);
  }
}

// ---------------------------------------------------------------------------
extern "C" void kernel_launch(void* const* d_in, const int* in_sizes, int n_in,
                              void* d_out, int out_size, void* d_ws, size_t ws_size,
                              hipStream_t stream) {
  const float* hs = (const float*)d_in[0];
  const float* cosb = (const float*)d_in[1];
  const float* sinb = (const float*)d_in[2];
  const float* w1 = (const float*)d_in[3];
  const float* wout = (const float*)d_in[4];
  const float* bout = (const float*)d_in[5];
  const float* nqw = (const float*)d_in[6];
  const float* nkw = (const float*)d_in[7];
  float* out = (float*)d_out;

  char* ws = (char*)d_ws;
  u16* X16 = (u16*)ws; ws += (size_t)4096 * 3072 * 2;
  u16* W1T = (u16*)ws; ws += (size_t)33792 * 3072 * 2;
  u16* WOT = (u16*)ws; ws += (size_t)3072 * 15360 * 2;
  u16* H   = (u16*)ws; ws += (size_t)4096 * 33792 * 2;   // reused as split-K partials
  u16* Qb  = (u16*)ws; ws += (size_t)24 * 4096 * 128 * 2;
  u16* Kb  = (u16*)ws; ws += (size_t)24 * 4096 * 128 * 2;
  u16* VTb = (u16*)ws; ws += (size_t)24 * 4096 * 128 * 2;
  u16* CC  = (u16*)ws; ws += (size_t)4096 * 15360 * 2;
  float* Pk = (float*)H;  // 4 x 4096 x 3072 fp32 = 201 MB <= H's 277 MB

  cast_bf16<<<6144, 256, 0, stream>>>(hs, X16);
  transpose_cast<<<(3072 / 64) * (33792 / 64), 256, 0, stream>>>(w1, W1T, 3072, 33792);
  transpose_cast<<<(15360 / 64) * (3072 / 64), 256, 0, stream>>>(wout, WOT, 15360, 3072);
  gemm8<0><<<(4096 / 256) * (33792 / 256), 512, 0, stream>>>(X16, W1T, H,
                                                             4096, 33792, 3072, 3072);
  qkv_prep<<<dim3(64, 24), 256, 0, stream>>>(H, cosb, sinb, nqw, nkw, Qb, Kb, VTb);
  mlp_act<<<(4096 * 12288 / 8) / 256, 256, 0, stream>>>(H, CC);
  attn_kernel<<<dim3(64, 24), 256, 0, stream>>>(Qb, Kb, VTb, CC);
  // GEMM2 split-K x4 (768 blocks = 3 full CU rounds), partials into Pk (=H)
  gemm8<1><<<dim3((4096 / 256) * (3072 / 256), 4), 512, 0, stream>>>(
      CC, WOT, Pk, 4096, 3072, 15360, 3840);
  reduce_bias<<<(4096 * 3072 / 4) / 256, 256, 0, stream>>>(Pk, bout, out);
}

// Round 6
// 1957.649 us; speedup vs baseline: 1.0751x; 1.0222x over previous
//
#include <hip/hip_runtime.h>

typedef short shortx8 __attribute__((ext_vector_type(8)));   // 8 bf16 (4 VGPRs)
typedef float floatx4 __attribute__((ext_vector_type(4)));
typedef unsigned short u16;

#define GLB(x) ((const __attribute__((address_space(1))) void*)(x))
#define LDSC(x) ((__attribute__((address_space(3))) void*)(x))
#define BAR() asm volatile("s_barrier" ::: "memory")
#define WAITV8() asm volatile("s_waitcnt vmcnt(8)" ::: "memory")

__device__ __forceinline__ float bf2f(u16 u) {
  unsigned x = ((unsigned)u) << 16;
  float f;
  __builtin_memcpy(&f, &x, 4);
  return f;
}
__device__ __forceinline__ u16 f2bf(float f) {
  unsigned x;
  __builtin_memcpy(&x, &f, 4);
  x += 0x7fffu + ((x >> 16) & 1u);   // RNE
  return (u16)(x >> 16);
}

// ---------------------------------------------------------------------------
// fp32 -> bf16 flat cast (X)
__global__ __launch_bounds__(256) void cast_bf16(const float* __restrict__ src,
                                                 u16* __restrict__ dst) {
  const size_t i = ((size_t)blockIdx.x * 256 + threadIdx.x) << 3;
  floatx4 a = *(const floatx4*)(src + i);
  floatx4 b = *(const floatx4*)(src + i + 4);
  shortx8 o;
#pragma unroll
  for (int e = 0; e < 4; ++e) {
    o[e] = (short)f2bf(a[e]);
    o[e + 4] = (short)f2bf(b[e]);
  }
  *(shortx8*)(dst + i) = o;
}

// ---------------------------------------------------------------------------
// fp32 [R][C] -> bf16 [C][R] tile transpose+cast (64x64 tiles via LDS)
__global__ __launch_bounds__(256) void transpose_cast(const float* __restrict__ src,
                                                      u16* __restrict__ dst,
                                                      int R, int C) {
  __shared__ u16 T[64 * 72];
  const int tiles_c = C >> 6;
  const int r0 = (blockIdx.x / tiles_c) << 6;
  const int c0 = (blockIdx.x % tiles_c) << 6;
  const int tid = threadIdx.x;
  const int rl = tid >> 4;
  const int cb = (tid & 15) << 2;
#pragma unroll
  for (int rr = 0; rr < 4; ++rr) {
    const int row = rr * 16 + rl;
    floatx4 v = *(const floatx4*)(src + (size_t)(r0 + row) * C + c0 + cb);
#pragma unroll
    for (int i = 0; i < 4; ++i) T[(cb + i) * 72 + row] = f2bf(v[i]);
  }
  __syncthreads();
#pragma unroll
  for (int ii = 0; ii < 2; ++ii) {
    const int chunk = tid + (ii << 8);
    const int cr = chunk >> 3;
    const int r8 = (chunk & 7) << 3;
    shortx8 v = *(const shortx8*)(T + cr * 72 + r8);
    *(shortx8*)(dst + (size_t)(c0 + cr) * R + r0 + r8) = v;
  }
}

// ---------------------------------------------------------------------------
// 256x256 8-phase bf16 GEMM (R2 schedule: 0 bank conflicts).
// B^T layout: C = A[M][K-chunk] * B^T([N][K-chunk]).  16x16x32 MFMA.
// MODE 0: bf16 C, full K.  MODE 1: fp32 partial (no bias), split-K chunk
// selected by blockIdx.y.  K-loop unrolled x2 so buffer parity (cur/nxt) is
// compile-time -> all LDS fragment addresses loop-invariant.
template <int MODE>
__global__ __launch_bounds__(512, 2) void gemm8(const u16* __restrict__ A,
                                                const u16* __restrict__ B,
                                                void* __restrict__ Cout,
                                                int M, int N, int K, int Ksub) {
  __shared__ u16 lds[8 * 8192];  // [buf][mat][ks][256*32] = 128 KiB

  const int nbm = M >> 8;
  const int nwg = nbm * (N >> 8);
  const int cpx = nwg >> 3;  // nwg % 8 == 0 for all our shapes
  const int wg = ((int)blockIdx.x & 7) * cpx + ((int)blockIdx.x >> 3);
  const int bm = wg % nbm;
  const int bn = wg / nbm;
  const int koff = (int)blockIdx.y * Ksub;

  const int tid = threadIdx.x;
  const int lane = tid & 63;
  const int w = tid >> 6;        // 0..7
  const int wm = w >> 2;         // 0..1
  const int wn = w & 3;          // 0..3
  const int l15 = lane & 15;
  const int l4 = lane >> 4;
  const int NT = Ksub >> 6;      // even for all our shapes (48, 60)

  const int lrow = lane >> 2;    // staging: 0..15
  const int lblk = lane & 3;

#define UNIT(buf, mat, ks) (lds + (((buf) * 4 + (mat) * 2 + (ks)) << 13))

  const u16* Abase = A + (size_t)bm * 256 * K + koff;
  const u16* Bbase = B + (size_t)bn * 256 * K + koff;

  auto STAGE = [&](int mat, int ks, int buf, int t) {
    const u16* gb = mat ? Bbase : Abase;
#pragma unroll
    for (int j = 0; j < 2; ++j) {
      const int row = (w * 2 + j) * 16 + lrow;
      const int sblk = lblk ^ ((row >> 1) & 3);
      const u16* src = gb + (size_t)row * K + (t << 6) + (ks << 5) + (sblk << 3);
      __builtin_amdgcn_global_load_lds(GLB(src),
                                       LDSC(UNIT(buf, mat, ks) + ((w * 2 + j) << 9)),
                                       16, 0, 0);
    }
  };
  auto LDA = [&](int mf, int ks, int buf) -> shortx8 {
    const int row = wm * 128 + mf * 16 + l15;
    return *(const shortx8*)(UNIT(buf, 0, ks) + row * 32 + ((l4 ^ ((row >> 1) & 3)) << 3));
  };
  auto LDB = [&](int nf, int ks, int buf) -> shortx8 {
    const int row = wn * 64 + nf * 16 + l15;
    return *(const shortx8*)(UNIT(buf, 1, ks) + row * 32 + ((l4 ^ ((row >> 1) & 3)) << 3));
  };

  floatx4 acc[8][4] = {};

  // Prologue: tile0 all 4 units, tile1 k0 units (oldest-first).
  STAGE(0, 0, 0, 0); STAGE(1, 0, 0, 0);
  STAGE(0, 1, 0, 0); STAGE(1, 1, 0, 0);
  STAGE(0, 0, 1, 1); STAGE(1, 0, 1, 1);
  WAITV8();
  BAR();

#pragma unroll 2
  for (int T = 0; T < NT; ++T) {
    const int cur = T & 1, nxt = cur ^ 1;
    const int t1 = (T + 1 < NT) ? T + 1 : NT - 1;
    const int t2 = (T + 2 < NT) ? T + 2 : NT - 1;
    shortx8 af[4], bf[4];

    // ---- phase q0: C-half0 x k0;  stage A-k1 of tile T+1 -> buf nxt
#pragma unroll
    for (int m = 0; m < 4; ++m) af[m] = LDA(m, 0, cur);
#pragma unroll
    for (int n = 0; n < 4; ++n) bf[n] = LDB(n, 0, cur);
    STAGE(0, 1, nxt, t1);
    BAR();
    __builtin_amdgcn_s_setprio(1);
#pragma unroll
    for (int m = 0; m < 4; ++m)
#pragma unroll
      for (int n = 0; n < 4; ++n)
        acc[m][n] = __builtin_amdgcn_mfma_f32_16x16x32_bf16(af[m], bf[n], acc[m][n], 0, 0, 0);
    __builtin_amdgcn_s_setprio(0);
    BAR();

    // ---- phase q1: C-half1 x k0 (B-frags reused);  stage B-k1 of T+1
#pragma unroll
    for (int m = 0; m < 4; ++m) af[m] = LDA(4 + m, 0, cur);
    STAGE(1, 1, nxt, t1);
    BAR();
    __builtin_amdgcn_s_setprio(1);
#pragma unroll
    for (int m = 0; m < 4; ++m)
#pragma unroll
      for (int n = 0; n < 4; ++n)
        acc[4 + m][n] = __builtin_amdgcn_mfma_f32_16x16x32_bf16(af[m], bf[n], acc[4 + m][n], 0, 0, 0);
    __builtin_amdgcn_s_setprio(0);
    WAITV8();
    BAR();

    // ---- phase q2: C-half0 x k1;  stage A-k0 of tile T+2 -> buf cur
#pragma unroll
    for (int m = 0; m < 4; ++m) af[m] = LDA(m, 1, cur);
#pragma unroll
    for (int n = 0; n < 4; ++n) bf[n] = LDB(n, 1, cur);
    STAGE(0, 0, cur, t2);
    BAR();
    __builtin_amdgcn_s_setprio(1);
#pragma unroll
    for (int m = 0; m < 4; ++m)
#pragma unroll
      for (int n = 0; n < 4; ++n)
        acc[m][n] = __builtin_amdgcn_mfma_f32_16x16x32_bf16(af[m], bf[n], acc[m][n], 0, 0, 0);
    __builtin_amdgcn_s_setprio(0);
    BAR();

    // ---- phase q3: C-half1 x k1;  stage B-k0 of T+2
#pragma unroll
    for (int m = 0; m < 4; ++m) af[m] = LDA(4 + m, 1, cur);
    STAGE(1, 0, cur, t2);
    BAR();
    __builtin_amdgcn_s_setprio(1);
#pragma unroll
    for (int m = 0; m < 4; ++m)
#pragma unroll
      for (int n = 0; n < 4; ++n)
        acc[4 + m][n] = __builtin_amdgcn_mfma_f32_16x16x32_bf16(af[m], bf[n], acc[4 + m][n], 0, 0, 0);
    __builtin_amdgcn_s_setprio(0);
    WAITV8();
    BAR();
  }

  // Epilogue
  const int orow0 = bm * 256 + wm * 128 + (l4 << 2);
  const int ocol0 = bn * 256 + wn * 64 + l15;
  if (MODE == 0) {
    u16* C = (u16*)Cout;
#pragma unroll
    for (int m = 0; m < 8; ++m)
#pragma unroll
      for (int n = 0; n < 4; ++n)
#pragma unroll
        for (int r = 0; r < 4; ++r)
          C[(size_t)(orow0 + m * 16 + r) * N + ocol0 + n * 16] = f2bf(acc[m][n][r]);
  } else {
    float* C = (float*)Cout + (size_t)blockIdx.y * M * N;
#pragma unroll
    for (int m = 0; m < 8; ++m)
#pragma unroll
      for (int n = 0; n < 4; ++n)
#pragma unroll
        for (int r = 0; r < 4; ++r)
          C[(size_t)(orow0 + m * 16 + r) * N + ocol0 + n * 16] = acc[m][n][r];
  }
}
#undef UNIT

// ---------------------------------------------------------------------------
// Split-K reduction: out = p0+p1+p2+p3 + bias
__global__ __launch_bounds__(256) void reduce_bias(const float* __restrict__ P,
                                                   const float* __restrict__ bias,
                                                   float* __restrict__ out) {
  const size_t base = ((size_t)blockIdx.x * 256 + threadIdx.x) << 2;
  const size_t stride = (size_t)4096 * 3072;
  floatx4 a = *(const floatx4*)(P + base);
  floatx4 b = *(const floatx4*)(P + stride + base);
  floatx4 c = *(const floatx4*)(P + 2 * stride + base);
  floatx4 d = *(const floatx4*)(P + 3 * stride + base);
  floatx4 bb = *(const floatx4*)(bias + (base % 3072));
  *(floatx4*)(out + base) = a + b + c + d + bb;
}

// ---------------------------------------------------------------------------
// RMSNorm + RoPE + scale fold for Q/K, V transpose to [H][D][S].
#define QSCALE (0.08838834764831845f * 1.4426950408889634f)  // 1/sqrt(128) * log2(e)

__global__ __launch_bounds__(256, 2) void qkv_prep(
    const u16* __restrict__ H, const float* __restrict__ cosb,
    const float* __restrict__ sinb, const float* __restrict__ nqw,
    const float* __restrict__ nkw, u16* __restrict__ Qo, u16* __restrict__ Ko,
    u16* __restrict__ Vo) {
  __shared__ u16 VT[128 * 72];
  const int head = blockIdx.y;
  const int t0 = blockIdx.x << 6;
  const int tid = threadIdx.x;
  const int tl = tid >> 2;
  const int db = (tid & 3) << 5;
  const int token = t0 + tl;

  const u16* hp = H + (size_t)token * 33792 + head * 128 + db;
  shortx8 qv[4], kvv[4], vv[4];
#pragma unroll
  for (int i = 0; i < 4; ++i) {
    qv[i] = *(const shortx8*)(hp + i * 8);
    kvv[i] = *(const shortx8*)(hp + 3072 + i * 8);
    vv[i] = *(const shortx8*)(hp + 6144 + i * 8);
  }
  float qx[32], kx[32];
  float sq = 0.f, sk = 0.f;
#pragma unroll
  for (int i = 0; i < 4; ++i)
#pragma unroll
    for (int j = 0; j < 8; ++j) {
      float a = bf2f((u16)qv[i][j]); qx[i * 8 + j] = a; sq += a * a;
      float b = bf2f((u16)kvv[i][j]); kx[i * 8 + j] = b; sk += b * b;
    }
  sq += __shfl_xor(sq, 1); sq += __shfl_xor(sq, 2);
  sk += __shfl_xor(sk, 1); sk += __shfl_xor(sk, 2);
  const float rq = rsqrtf(sq * (1.0f / 128.0f) + 1e-5f);
  const float rk = rsqrtf(sk * (1.0f / 128.0f) + 1e-5f);

  shortx8 oqv[4], okv[4];
#pragma unroll
  for (int p = 0; p < 16; ++p) {
    const float c = cosb[(size_t)token * 64 + (db >> 1) + p];
    const float s = sinb[(size_t)token * 64 + (db >> 1) + p];
    const int vi = p >> 2, vj = (p & 3) << 1;
    float a1 = qx[2 * p] * rq * nqw[db + 2 * p];
    float a2 = qx[2 * p + 1] * rq * nqw[db + 2 * p + 1];
    oqv[vi][vj] = (short)f2bf((a1 * c - a2 * s) * QSCALE);
    oqv[vi][vj + 1] = (short)f2bf((a2 * c + a1 * s) * QSCALE);
    float b1 = kx[2 * p] * rk * nkw[db + 2 * p];
    float b2 = kx[2 * p + 1] * rk * nkw[db + 2 * p + 1];
    okv[vi][vj] = (short)f2bf(b1 * c - b2 * s);
    okv[vi][vj + 1] = (short)f2bf(b2 * c + b1 * s);
  }
  {
    u16* qo = Qo + (size_t)head * 4096 * 128 + (size_t)token * 128 + db;
    u16* ko = Ko + (size_t)head * 4096 * 128 + (size_t)token * 128 + db;
#pragma unroll
    for (int i = 0; i < 4; ++i) {
      *(shortx8*)(qo + i * 8) = oqv[i];
      *(shortx8*)(ko + i * 8) = okv[i];
    }
  }
#pragma unroll
  for (int i = 0; i < 4; ++i)
#pragma unroll
    for (int j = 0; j < 8; ++j) VT[(db + i * 8 + j) * 72 + tl] = (u16)vv[i][j];
  __syncthreads();
#pragma unroll
  for (int ii = 0; ii < 4; ++ii) {
    const int chunk = tid + (ii << 8);
    const int d = chunk >> 3;
    const int j8 = (chunk & 7) << 3;
    shortx8 v = *(const shortx8*)(VT + d * 72 + j8);
    *(shortx8*)(Vo + (size_t)head * 128 * 4096 + (size_t)d * 4096 + t0 + j8) = v;
  }
}

// ---------------------------------------------------------------------------
// SiLU gate: CC[t][3072+j] = silu(m1)*m2
__global__ __launch_bounds__(256) void mlp_act(const u16* __restrict__ H,
                                               u16* __restrict__ CC) {
  const size_t id = (size_t)blockIdx.x * 256 + threadIdx.x;
  const int t = (int)(id / 1536);
  const int j = ((int)(id % 1536)) << 3;
  const u16* base = H + (size_t)t * 33792;
  shortx8 a = *(const shortx8*)(base + 9216 + j);
  shortx8 b = *(const shortx8*)(base + 21504 + j);
  shortx8 o;
#pragma unroll
  for (int e = 0; e < 8; ++e) {
    float x = bf2f((u16)a[e]);
    float y = bf2f((u16)b[e]);
    float sg = 1.0f / (1.0f + exp2f(-1.4426950408889634f * x));
    o[e] = (short)f2bf(x * sg * y);
  }
  *(shortx8*)(CC + (size_t)t * 15360 + 3072 + j) = o;
}

// ---------------------------------------------------------------------------
// Flash attention: grid (64 q-tiles, 24 heads), 4 waves x 16 q-rows,
// KV tile 128 (32 iterations).  K[128][128] / V[128][128] / P[16][128]
// XOR-swizzled in 16B blocks (blk ^= row&7); K/V staged with pre-swizzled
// global source + linear global_load_lds dest.  LDS 80KB -> 2 blocks/CU.
__global__ __launch_bounds__(256, 2) void attn_kernel(const u16* __restrict__ Qg,
                                                      const u16* __restrict__ Kg,
                                                      const u16* __restrict__ Vg,
                                                      u16* __restrict__ CC) {
  __shared__ u16 Ks[128 * 128];   // [kv][d]
  __shared__ u16 Vs[128 * 128];   // [d][kv]
  __shared__ u16 Ps[4 * 16 * 128];

  const int head = blockIdx.y;
  const int q0 = blockIdx.x << 6;
  const int tid = threadIdx.x;
  const int lane = tid & 63;
  const int wave = tid >> 6;
  const int l15 = lane & 15;
  const int l4 = lane >> 4;

  const u16* Qh = Qg + (size_t)head * 4096 * 128;
  const u16* Kh = Kg + (size_t)head * 4096 * 128;
  const u16* Vh = Vg + (size_t)head * 128 * 4096;

  shortx8 qf[4];
  {
    const u16* qp = Qh + (size_t)(q0 + wave * 16 + l15) * 128 + l4 * 8;
#pragma unroll
    for (int ks = 0; ks < 4; ++ks) qf[ks] = *(const shortx8*)(qp + ks * 32);
  }

  floatx4 o[8] = {};
  float mrun[4], lrun[4];
#pragma unroll
  for (int r = 0; r < 4; ++r) { mrun[r] = -1e30f; lrun[r] = 0.0f; }

  u16* Pw = Ps + wave * 2048;
  const int swz = l15 & 7;

  for (int s0 = 0; s0 < 4096; s0 += 128) {
    // stage K[128][128]: 32 chunks of 4 rows; wave handles 8
#pragma unroll
    for (int i = 0; i < 8; ++i) {
      const int c = wave * 8 + i;
      const int row = c * 4 + (lane >> 4);
      const int blk = (lane & 15) ^ (row & 7);
      __builtin_amdgcn_global_load_lds(GLB(Kh + (size_t)(s0 + row) * 128 + blk * 8),
                                       LDSC(Ks + c * 512), 16, 0, 0);
    }
    // stage V[128 d][128 kv]: 32 chunks of 4 rows; wave handles 8
#pragma unroll
    for (int i = 0; i < 8; ++i) {
      const int c = wave * 8 + i;
      const int row = c * 4 + (lane >> 4);
      const int blk = (lane & 15) ^ (row & 7);
      __builtin_amdgcn_global_load_lds(GLB(Vh + (size_t)row * 4096 + s0 + blk * 8),
                                       LDSC(Vs + c * 512), 16, 0, 0);
    }
    __syncthreads();

    // S = Q K^T (scaled via Q), rows 4*l4+r, cols n*16+l15
    floatx4 s[8];
    __builtin_amdgcn_s_setprio(1);
#pragma unroll
    for (int n = 0; n < 8; ++n) {
      const int krow = n * 16 + l15;
      floatx4 acc = {};
#pragma unroll
      for (int ks = 0; ks < 4; ++ks) {
        shortx8 kf = *(const shortx8*)(Ks + krow * 128 + (((ks * 4 + l4) ^ swz) << 3));
        acc = __builtin_amdgcn_mfma_f32_16x16x32_bf16(qf[ks], kf, acc, 0, 0, 0);
      }
      s[n] = acc;
    }
    __builtin_amdgcn_s_setprio(0);

    float alpha[4];
#pragma unroll
    for (int r = 0; r < 4; ++r) {
      float v = fmaxf(fmaxf(fmaxf(s[0][r], s[1][r]), fmaxf(s[2][r], s[3][r])),
                      fmaxf(fmaxf(s[4][r], s[5][r]), fmaxf(s[6][r], s[7][r])));
      v = fmaxf(v, __shfl_xor(v, 1));
      v = fmaxf(v, __shfl_xor(v, 2));
      v = fmaxf(v, __shfl_xor(v, 4));
      v = fmaxf(v, __shfl_xor(v, 8));
      const float mn = fmaxf(mrun[r], v);
      alpha[r] = exp2f(mrun[r] - mn);
      mrun[r] = mn;
    }

    float rs[4] = {0.f, 0.f, 0.f, 0.f};
#pragma unroll
    for (int n = 0; n < 8; ++n) {
#pragma unroll
      for (int r = 0; r < 4; ++r) {
        const float p = exp2f(s[n][r] - mrun[r]);
        rs[r] += p;
        const int prow = (l4 << 2) + r;
        const int pblk = ((n << 1) + (l15 >> 3)) ^ (prow & 7);
        Pw[prow * 128 + (pblk << 3) + (l15 & 7)] = f2bf(p);
      }
    }
#pragma unroll
    for (int r = 0; r < 4; ++r) {
      float v = rs[r];
      v += __shfl_xor(v, 1);
      v += __shfl_xor(v, 2);
      v += __shfl_xor(v, 4);
      v += __shfl_xor(v, 8);
      lrun[r] = lrun[r] * alpha[r] + v;
    }
    // Lossless defer-rescale: when no lane's max advanced, all alpha == 1.0f.
    if (__any((alpha[0] < 1.0f) || (alpha[1] < 1.0f) ||
              (alpha[2] < 1.0f) || (alpha[3] < 1.0f))) {
#pragma unroll
      for (int nd = 0; nd < 8; ++nd)
#pragma unroll
        for (int r = 0; r < 4; ++r) o[nd][r] *= alpha[r];
    }

    // O += P V
    shortx8 pf[4];
#pragma unroll
    for (int ks = 0; ks < 4; ++ks)
      pf[ks] = *(const shortx8*)(Pw + l15 * 128 + (((ks * 4 + l4) ^ swz) << 3));
    __builtin_amdgcn_s_setprio(1);
#pragma unroll
    for (int nd = 0; nd < 8; ++nd) {
      const int vrow = nd * 16 + l15;
#pragma unroll
      for (int ks = 0; ks < 4; ++ks) {
        shortx8 vf = *(const shortx8*)(Vs + vrow * 128 + (((ks * 4 + l4) ^ swz) << 3));
        o[nd] = __builtin_amdgcn_mfma_f32_16x16x32_bf16(pf[ks], vf, o[nd], 0, 0, 0);
      }
    }
    __builtin_amdgcn_s_setprio(0);
    __syncthreads();
  }

#pragma unroll
  for (int r = 0; r < 4; ++r) {
    const float inv = 1.0f / lrun[r];
    const int row = q0 + wave * 16 + (l4 << 2) + r;
    u16* outp = CC + (size_t)row * 15360 + head * 128 + l15;
#pragma unroll
    for (int nd = 0; nd < 8; ++nd) outp[nd << 4] = f2bf(o[nd][r] * inv);
  }
}

// ---------------------------------------------------------------------------
extern "C" void kernel_launch(void* const* d_in, const int* in_sizes, int n_in,
                              void* d_out, int out_size, void* d_ws, size_t ws_size,
                              hipStream_t stream) {
  const float* hs = (const float*)d_in[0];
  const float* cosb = (const float*)d_in[1];
  const float* sinb = (const float*)d_in[2];
  const float* w1 = (const float*)d_in[3];
  const float* wout = (const float*)d_in[4];
  const float* bout = (const float*)d_in[5];
  const float* nqw = (const float*)d_in[6];
  const float* nkw = (const float*)d_in[7];
  float* out = (float*)d_out;

  char* ws = (char*)d_ws;
  u16* X16 = (u16*)ws; ws += (size_t)4096 * 3072 * 2;
  u16* W1T = (u16*)ws; ws += (size_t)33792 * 3072 * 2;
  u16* WOT = (u16*)ws; ws += (size_t)3072 * 15360 * 2;
  u16* H   = (u16*)ws; ws += (size_t)4096 * 33792 * 2;   // reused as split-K partials
  u16* Qb  = (u16*)ws; ws += (size_t)24 * 4096 * 128 * 2;
  u16* Kb  = (u16*)ws; ws += (size_t)24 * 4096 * 128 * 2;
  u16* VTb = (u16*)ws; ws += (size_t)24 * 4096 * 128 * 2;
  u16* CC  = (u16*)ws; ws += (size_t)4096 * 15360 * 2;
  float* Pk = (float*)H;  // 4 x 4096 x 3072 fp32 = 201 MB <= H's 277 MB

  cast_bf16<<<6144, 256, 0, stream>>>(hs, X16);
  transpose_cast<<<(3072 / 64) * (33792 / 64), 256, 0, stream>>>(w1, W1T, 3072, 33792);
  transpose_cast<<<(15360 / 64) * (3072 / 64), 256, 0, stream>>>(wout, WOT, 15360, 3072);
  gemm8<0><<<(4096 / 256) * (33792 / 256), 512, 0, stream>>>(X16, W1T, H,
                                                             4096, 33792, 3072, 3072);
  qkv_prep<<<dim3(64, 24), 256, 0, stream>>>(H, cosb, sinb, nqw, nkw, Qb, Kb, VTb);
  mlp_act<<<(4096 * 12288 / 8) / 256, 256, 0, stream>>>(H, CC);
  attn_kernel<<<dim3(64, 24), 256, 0, stream>>>(Qb, Kb, VTb, CC);
  // GEMM2 split-K x4 (768 blocks = 3 full CU rounds), partials into Pk (=H)
  gemm8<1><<<dim3((4096 / 256) * (3072 / 256), 4), 512, 0, stream>>>(
      CC, WOT, Pk, 4096, 3072, 15360, 3840);
  reduce_bias<<<(4096 * 3072 / 4) / 256, 256, 0, stream>>>(Pk, bout, out);
}